// Round 11
// baseline (83.765 us; speedup 1.0000x reference)
//
#include <hip/hip_runtime.h>

constexpr float EPS = 1e-5f;

typedef __attribute__((ext_vector_type(8))) short bf16x8;
typedef __attribute__((ext_vector_type(4))) float f32x4;

// d_ws layout (bytes):
//   0      : w3p[8nt][4ks][64][8]   bf16 BN-folded (R10-verbatim; k = ks*32+g*8+e; ks2,3 = agg rows)
//   32768  : w2Tlo[4mc][64][8]      bf16 W2^T rows 0-15 (h1 part), BN-folded, k-slots>=16 ZERO
//   36864  : w2Thi[4mc][64][8]      bf16 W2^T rows 16-31 (agg part), k-slots>=16 ZERO
//   40960  : w1T[64][8]             bf16 W1^T, BN-folded, k-slots>=8 ZERO
//   41984  : bb1 f32[16] ; 42048: bb2 f32[64] ; 42304: bb3 f32[128]
#define W2TL_OFF 32768
#define W2TH_OFF 36864
#define W1T_OFF  40960
#define B1_OFF   41984
#define B2_OFF   42048
#define B3_OFF   42304

__device__ __forceinline__ ushort f2bf(float x) {
    union { float f; unsigned u; } a; a.f = x;
    unsigned r = a.u + 0x7fffu + ((a.u >> 16) & 1u);   // RTNE (finite only)
    return (ushort)(r >> 16);
}

__device__ __forceinline__ unsigned cvtpk(float lo, float hi) {
    unsigned r;
    asm("v_cvt_pk_bf16_f32 %0, %1, %2" : "=v"(r) : "v"(lo), "v"(hi));
    return r;
}

__device__ __forceinline__ f32x4 vmax4(f32x4 a, f32x4 b) {
    f32x4 r;
    r[0] = fmaxf(a[0], b[0]); r[1] = fmaxf(a[1], b[1]);
    r[2] = fmaxf(a[2], b[2]); r[3] = fmaxf(a[3], b[3]);
    return r;
}

__device__ __forceinline__ f32x4 shflx4(f32x4 v, int m) {
    f32x4 r;
    r[0] = __shfl_xor(v[0], m); r[1] = __shfl_xor(v[1], m);
    r[2] = __shfl_xor(v[2], m); r[3] = __shfl_xor(v[3], m);
    return r;
}

__global__ void vfe_prep(
    const float* __restrict__ w1, const float* __restrict__ b1,
    const float* __restrict__ g1, const float* __restrict__ be1,
    const float* __restrict__ m1, const float* __restrict__ v1,
    const float* __restrict__ w2, const float* __restrict__ b2,
    const float* __restrict__ g2, const float* __restrict__ be2,
    const float* __restrict__ m2, const float* __restrict__ v2,
    const float* __restrict__ w3, const float* __restrict__ b3,
    const float* __restrict__ g3, const float* __restrict__ be3,
    const float* __restrict__ m3, const float* __restrict__ v3,
    void* __restrict__ ws)
{
    ushort* w3p  = (ushort*)ws;
    ushort* w2tl = (ushort*)((char*)ws + W2TL_OFF);
    ushort* w2th = (ushort*)((char*)ws + W2TH_OFF);
    ushort* w1t  = (ushort*)((char*)ws + W1T_OFF);
    float*  bb1  = (float*)((char*)ws + B1_OFF);
    float*  bb2  = (float*)((char*)ws + B2_OFF);
    float*  bb3  = (float*)((char*)ws + B3_OFF);

    const int i = blockIdx.x * 256 + threadIdx.x;
    if (i < 16384) {                       // w3p: ((nt*4+ks)*64 + l)*8 + e  (R10-verbatim)
        const int e = i & 7, l = (i >> 3) & 63, rest = i >> 9;
        const int ks = rest & 3, nt = rest >> 2, g = l >> 4;
        const int k = ks * 32 + g * 8 + e;
        const int n = nt * 16 + (l & 15);
        const float s = g3[n] * rsqrtf(v3[n] + EPS);
        w3p[i] = f2bf(w3[k * 128 + n] * s);
    } else if (i < 18432) {                // w2Tlo: (mc*64 + l)*8 + e
        const int j = i - 16384;
        const int e = j & 7, l = (j >> 3) & 63, mc = j >> 9;
        const int slot = (l >> 4) * 8 + e;             // x1-channel, real <16
        const int m = mc * 16 + (l & 15);              // h2 channel (output)
        const float s = g2[m] * rsqrtf(v2[m] + EPS);
        w2tl[j] = (slot < 16) ? f2bf(w2[slot * 64 + m] * s) : (ushort)0;
    } else if (i < 20480) {                // w2Thi: agg rows 16-31
        const int j = i - 18432;
        const int e = j & 7, l = (j >> 3) & 63, mc = j >> 9;
        const int slot = (l >> 4) * 8 + e;
        const int m = mc * 16 + (l & 15);
        const float s = g2[m] * rsqrtf(v2[m] + EPS);
        w2th[j] = (slot < 16) ? f2bf(w2[(16 + slot) * 64 + m] * s) : (ushort)0;
    } else if (i < 20992) {                // w1T: l*8 + e
        const int j = i - 20480;
        const int e = j & 7, l = j >> 3;
        const int slot = (l >> 4) * 8 + e;             // x0-channel, real <8
        const int m = l & 15;                          // h1 channel
        const float s = g1[m] * rsqrtf(v1[m] + EPS);
        w1t[j] = (slot < 8) ? f2bf(w1[slot * 16 + m] * s) : (ushort)0;
    } else if (i < 21200) {
        const int j = i - 20992;
        if (j < 16) {
            const int u = j;
            bb1[u] = (b1[u] - m1[u]) * (g1[u] * rsqrtf(v1[u] + EPS)) + be1[u];
        } else if (j < 80) {
            const int u = j - 16;
            bb2[u] = (b2[u] - m2[u]) * (g2[u] * rsqrtf(v2[u] + EPS)) + be2[u];
        } else {
            const int u = j - 80;
            bb3[u] = (b3[u] - m3[u]) * (g3[u] * rsqrtf(v3[u] + EPS)) + be3[u];
        }
    }
}

#define NV(v)   ((v)==0?nv0:(v)==1?nv1:(v)==2?nv2:nv3)
#define LIM(v)  ((v)==0?lim0:(v)==1?lim1:(v)==2?lim2:lim3)
#define FULL(v) ((v)==0?full0:(v)==1?full1:(v)==2?full2:full3)

// 4 voxels/block, wave w owns voxel w through L1/L2/agg; L3 column-partitioned.
// ONE __syncthreads (before L3).
__global__ __launch_bounds__(256, 4) void vfe_fused(
    const float* __restrict__ feat,
    const int* __restrict__ nvox,
    const void* __restrict__ ws,
    float* __restrict__ out,
    int K)
{
    // sBfrag: h2^T, [12 tiles][16 t-rows][64 ch] bf16, XOR-swizzled rows.
    // Wave w's stage-0 x0 rows are unioned into the head of its own tile w*3+0
    // (768 B < 2048 B; dead before the L2 nt=0 rewrite; wave-private, in-order LDS).
    __shared__ __align__(16) ushort sBfrag[12 * 16 * 64];
    __shared__ __align__(16) ushort sAfrag[12 * 16 * 16];   // h1^T: [tile][t][16 ch]
    __shared__ __align__(16) ushort sAgg2bf[4 * 64];        // agg2 per voxel, bf16

    const ushort* w3p  = (const ushort*)ws;
    const ushort* w2tl = (const ushort*)((const char*)ws + W2TL_OFF);
    const ushort* w2th = (const ushort*)((const char*)ws + W2TH_OFF);
    const ushort* w1t  = (const ushort*)((const char*)ws + W1T_OFF);
    const float*  bb1  = (const float*)((const char*)ws + B1_OFF);
    const float*  bb2  = (const float*)((const char*)ws + B2_OFF);
    const float*  bb3  = (const float*)((const char*)ws + B3_OFF);

    const int tid  = threadIdx.x;
    const int lane = tid & 63;
    const int w    = tid >> 6;
    const int g    = lane >> 4;
    const int m15  = lane & 15;
    const int kA   = blockIdx.x * 4;

    const int kk0 = kA, kk1 = min(kA+1, K-1), kk2 = min(kA+2, K-1), kk3 = min(kA+3, K-1);
    const int nv0 = __builtin_amdgcn_readfirstlane(nvox[kk0]);
    const int nv1 = __builtin_amdgcn_readfirstlane(nvox[kk1]);
    const int nv2 = __builtin_amdgcn_readfirstlane(nvox[kk2]);
    const int nv3 = __builtin_amdgcn_readfirstlane(nvox[kk3]);
    const int lim0=(nv0+15)>>4, lim1=(nv1+15)>>4, lim2=(nv2+15)>>4, lim3=(nv3+15)>>4;
    const int full0=nv0>>4, full1=nv1>>4, full2=nv2>>4, full3=nv3>>4;

    const int kkw   = (w==0)?kk0:(w==1)?kk1:(w==2)?kk2:kk3;
    const int nvw   = (w==0)?nv0:(w==1)?nv1:(w==2)?nv2:nv3;
    const int limw  = (nvw + 15) >> 4;
    const int fullw = nvw >> 4;

    union U8 { bf16x8 v; unsigned u[4]; };

    // ---- stage 0: wave-private, x0^T rows into head of own sBfrag tile ----
    ushort* sX0w = &sBfrag[w * 3 * 1024];          // tile = 16*64 ushorts
    {
        float4 f = make_float4(0.f, 0.f, 0.f, 0.f);
        if (lane < 48)
            f = *reinterpret_cast<const float4*>(feat + ((size_t)kkw * 48 + lane) * 4);
        float sx = f.x, sy = f.y, sz = f.z;
        #pragma unroll
        for (int d = 1; d < 64; d <<= 1) {
            sx += __shfl_xor(sx, d);
            sy += __shfl_xor(sy, d);
            sz += __shfl_xor(sz, d);
        }
        const float inv = 1.f / (float)nvw;
        if (lane < 48) {
            const float msk = (lane < nvw) ? 1.f : 0.f;
            const float dd = sqrtf(f.x * f.x + f.y * f.y + f.z * f.z);
            U8 a;
            a.u[0] = cvtpk(f.x * msk, f.y * msk);
            a.u[1] = cvtpk(f.z * msk, f.w * msk);
            a.u[2] = cvtpk((f.x - sx * inv) * msk, (f.y - sy * inv) * msk);
            a.u[3] = cvtpk((f.z - sz * inv) * msk, dd * msk);
            *reinterpret_cast<bf16x8*>(sX0w + (size_t)lane * 8) = a.v;
        }
    }

    // ---- layer 1 (swapped): h1^T = W1^T . x0^T ; C-init = bb1 rows ----
    const bf16x8 w1f = *(const bf16x8*)(w1t + (size_t)lane * 8);
    const f32x4 bb1v = *(const f32x4*)(bb1 + g * 4);     // row channels g*4+r
    f32x4 agg1 = vmax4(bb1v, (f32x4){0.f,0.f,0.f,0.f});  // analytic masked-row term
    #pragma unroll
    for (int nt = 0; nt < 3; ++nt) {
        if (nt < limw) {
            // B-frag: col=t(m15), k-slots g*8+e; real x0-ch<8 so read row bytes [0,16) for all g (broadcast)
            const bf16x8 x0b = *(const bf16x8*)(sX0w + (size_t)(nt * 16 + m15) * 8);
            f32x4 acc = __builtin_amdgcn_mfma_f32_16x16x32_bf16(w1f, x0b, bb1v, 0, 0, 0);
            f32x4 h = vmax4(acc, (f32x4){0.f,0.f,0.f,0.f});   // rows t>=nv -> relu(bb1) (x0=0)
            agg1 = vmax4(agg1, h);
            // write h1^T: [tile][t=m15][ch g*4..g*4+3], b64
            *reinterpret_cast<uint2*>(sAfrag + (size_t)(w * 3 + nt) * 256 + m15 * 16 + g * 4) =
                make_uint2(cvtpk(h[0], h[1]), cvtpk(h[2], h[3]));
        }
    }
    // agg1: max over t (cross-m15 all-reduce); lane (m15,g) -> agg1[g*4+r]
    #pragma unroll
    for (int s = 1; s < 16; s <<= 1) agg1 = vmax4(agg1, shflx4(agg1, s));

    // ---- z2-fold: B-frag = agg1 at k-slots (ch = g*8+e, real <16) ----
    f32x4 z2acc[4];
    f32x4 bb2v[4];
    {
        const int src0 = ((g * 2)     & 3) * 16 + m15;
        const int src1 = ((g * 2 + 1) & 3) * 16 + m15;
        const float a0 = __shfl(agg1[0], src0), a1 = __shfl(agg1[1], src0);
        const float a2 = __shfl(agg1[2], src0), a3 = __shfl(agg1[3], src0);
        const float c0 = __shfl(agg1[0], src1), c1 = __shfl(agg1[1], src1);
        const float c2 = __shfl(agg1[2], src1), c3 = __shfl(agg1[3], src1);
        U8 az2;
        az2.u[0] = cvtpk(a0, a1); az2.u[1] = cvtpk(a2, a3);
        az2.u[2] = cvtpk(c0, c1); az2.u[3] = cvtpk(c2, c3);
        #pragma unroll
        for (int mc = 0; mc < 4; ++mc) {
            bb2v[mc] = *(const f32x4*)(bb2 + mc * 16 + g * 4);
            const bf16x8 whi = *(const bf16x8*)(w2th + (size_t)(mc * 64 + lane) * 8);
            z2acc[mc] = __builtin_amdgcn_mfma_f32_16x16x32_bf16(whi, az2.v, bb2v[mc], 0, 0, 0);
        }
    }

    // ---- layer 2 (swapped): h2^T = W2^T . x1^T ; C-init = bb2+z2 ----
    f32x4 agg2acc[4];
    #pragma unroll
    for (int mc = 0; mc < 4; ++mc) agg2acc[mc] = vmax4(bb2v[mc], (f32x4){0.f,0.f,0.f,0.f});
    {
        bf16x8 wlo[4];
        #pragma unroll
        for (int mc = 0; mc < 4; ++mc)
            wlo[mc] = *(const bf16x8*)(w2tl + (size_t)(mc * 64 + lane) * 8);
        const int swz = (m15 & 7) << 4;
        #pragma unroll
        for (int nt = 0; nt < 3; ++nt) {
            if (nt < limw) {
                // B-frag: real x1-ch<16: bytes [(g&1)*16, +16) of h1^T row
                const bf16x8 xb = *(const bf16x8*)(sAfrag + (size_t)(w * 3 + nt) * 256 + m15 * 16 + (g & 1) * 8);
                f32x4 h[4];
                #pragma unroll
                for (int mc = 0; mc < 4; ++mc) {
                    f32x4 acc = __builtin_amdgcn_mfma_f32_16x16x32_bf16(wlo[mc], xb, z2acc[mc], 0, 0, 0);
                    h[mc] = vmax4(acc, (f32x4){0.f,0.f,0.f,0.f});
                }
                if (nt < fullw) {
                    #pragma unroll
                    for (int mc = 0; mc < 4; ++mc) agg2acc[mc] = vmax4(agg2acc[mc], h[mc]);
                } else {
                    const bool p = (nt * 16 + m15) < nvw;
                    #pragma unroll
                    for (int mc = 0; mc < 4; ++mc) {
                        #pragma unroll
                        for (int r = 0; r < 4; ++r)
                            agg2acc[mc][r] = p ? fmaxf(agg2acc[mc][r], h[mc][r]) : agg2acc[mc][r];
                    }
                }
                // pack + swizzled b64 writes: row byte-off = (mc*32+g*8) ^ swz
                char* rowp = (char*)sBfrag + (size_t)(w * 3 + nt) * 2048 + m15 * 128;
                #pragma unroll
                for (int mc = 0; mc < 4; ++mc)
                    *reinterpret_cast<uint2*>(rowp + ((mc * 32 + g * 8) ^ swz)) =
                        make_uint2(cvtpk(h[mc][0], h[mc][1]), cvtpk(h[mc][2], h[mc][3]));
            }
        }
    }
    // agg2 all-reduce over m15; write own voxel's sAgg2bf
    #pragma unroll
    for (int s = 1; s < 16; s <<= 1) {
        #pragma unroll
        for (int mc = 0; mc < 4; ++mc) agg2acc[mc] = vmax4(agg2acc[mc], shflx4(agg2acc[mc], s));
    }
    if (m15 < 4) {
        const f32x4 v = (m15==0)?agg2acc[0]:(m15==1)?agg2acc[1]:(m15==2)?agg2acc[2]:agg2acc[3];
        *reinterpret_cast<uint2*>((char*)sAgg2bf + w * 128 + m15 * 32 + g * 8) =
            make_uint2(cvtpk(v[0], v[1]), cvtpk(v[2], v[3]));
    }
    __syncthreads();   // the ONLY barrier: sBfrag + sAgg2bf now visible to all waves

    // ---- L3 B-frag preloads (R10-verbatim w3p bijection) ----
    bf16x8 b3f[2][4];
    #pragma unroll
    for (int nt = 0; nt < 2; ++nt)
        #pragma unroll
        for (int ks = 0; ks < 4; ++ks)
            b3f[nt][ks] = *(const bf16x8*)(w3p + (size_t)(((w * 2 + nt) * 4 + ks) * 64 + lane) * 8);

    // ---- z3-fold (R10-verbatim): A rows cycle voxels -> C reg r = voxel r ----
    f32x4 i3[2];
    #pragma unroll
    for (int nt = 0; nt < 2; ++nt) {
        const float bb3c = bb3[(w * 2 + nt) * 16 + m15];
        f32x4 z = {bb3c, bb3c, bb3c, bb3c};
        #pragma unroll
        for (int ks2 = 0; ks2 < 2; ++ks2) {
            const bf16x8 af = *(const bf16x8*)(sAgg2bf + (size_t)(m15 & 3) * 64 + ks2 * 32 + g * 8);
            z = __builtin_amdgcn_mfma_f32_16x16x32_bf16(af, b3f[nt][2 + ks2], z, 0, 0, 0);
        }
        i3[nt] = z;
    }

    // ---- layer 3: 2 passes x two 6-tile halves (R10 structure, new A-frag reads) ----
    const int swzr = (m15 & 7) << 4;
    #pragma unroll
    for (int pass = 0; pass < 2; ++pass) {
        const int col = (w * 2 + pass) * 16 + m15;
        #pragma unroll
        for (int vg = 0; vg < 2; ++vg) {
            f32x4 acc3[6];
            #pragma unroll
            for (int j = 0; j < 6; ++j) {
                const int tt = vg * 6 + j;              // == vox*3 + mtl
                const int vox = vg * 2 + j / 3;
                const int mtl = j % 3;
                if (mtl < LIM(vox)) {
                    const char* base = (const char*)sBfrag + (size_t)tt * 2048 + m15 * 128;
                    const bf16x8 af0 = *(const bf16x8*)(base + ((g * 16) ^ swzr));
                    const bf16x8 af1 = *(const bf16x8*)(base + ((64 + g * 16) ^ swzr));
                    const float ci = i3[pass][vox];
                    f32x4 c = {ci, ci, ci, ci};
                    acc3[j] = __builtin_amdgcn_mfma_f32_16x16x32_bf16(af0, b3f[pass][0], c, 0, 0, 0);
                    acc3[j] = __builtin_amdgcn_mfma_f32_16x16x32_bf16(af1, b3f[pass][1], acc3[j], 0, 0, 0);
                }
            }
            float mxP = 0.f, mxQ = 0.f;   // relu folded into fmax (mx >= 0)
            #pragma unroll
            for (int j = 0; j < 6; ++j) {
                const int vox = vg * 2 + j / 3;
                const int mtl = j % 3;
                if (mtl < FULL(vox)) {
                    const float t01 = fmaxf(acc3[j][0], acc3[j][1]);
                    const float t23 = fmaxf(acc3[j][2], acc3[j][3]);
                    if (j < 3) mxP = fmaxf(mxP, fmaxf(t01, t23));
                    else       mxQ = fmaxf(mxQ, fmaxf(t01, t23));
                } else if (mtl < LIM(vox)) {
                    #pragma unroll
                    for (int r = 0; r < 4; ++r) {
                        if (mtl * 16 + g * 4 + r < NV(vox)) {
                            if (j < 3) mxP = fmaxf(mxP, acc3[j][r]);
                            else       mxQ = fmaxf(mxQ, acc3[j][r]);
                        }
                    }
                }
            }
            mxP = fmaxf(mxP, __shfl_xor(mxP, 16));
            mxP = fmaxf(mxP, __shfl_xor(mxP, 32));
            mxQ = fmaxf(mxQ, __shfl_xor(mxQ, 16));
            mxQ = fmaxf(mxQ, __shfl_xor(mxQ, 32));
            if (g == (vg * 2 + 0) && (kA + vg * 2 + 0) < K) out[(size_t)(kA + vg * 2 + 0) * 128 + col] = mxP;
            if (g == (vg * 2 + 1) && (kA + vg * 2 + 1) < K) out[(size_t)(kA + vg * 2 + 1) * 128 + col] = mxQ;
        }
    }
}

extern "C" void kernel_launch(void* const* d_in, const int* in_sizes, int n_in,
                              void* d_out, int out_size, void* d_ws, size_t ws_size,
                              hipStream_t stream) {
    const float* feat = (const float*)d_in[0];
    const int*   nvx  = (const int*)d_in[1];
    const float* w1 = (const float*)d_in[3];
    const float* b1 = (const float*)d_in[4];
    const float* g1 = (const float*)d_in[5];
    const float* be1= (const float*)d_in[6];
    const float* m1 = (const float*)d_in[7];
    const float* v1 = (const float*)d_in[8];
    const float* w2 = (const float*)d_in[9];
    const float* b2 = (const float*)d_in[10];
    const float* g2 = (const float*)d_in[11];
    const float* be2= (const float*)d_in[12];
    const float* m2 = (const float*)d_in[13];
    const float* v2 = (const float*)d_in[14];
    const float* w3 = (const float*)d_in[15];
    const float* b3 = (const float*)d_in[16];
    const float* g3 = (const float*)d_in[17];
    const float* be3= (const float*)d_in[18];
    const float* m3 = (const float*)d_in[19];
    const float* v3 = (const float*)d_in[20];
    float* out = (float*)d_out;

    const int K = in_sizes[1];

    vfe_prep<<<84, 256, 0, stream>>>(w1,b1,g1,be1,m1,v1, w2,b2,g2,be2,m2,v2,
                                     w3,b3,g3,be3,m3,v3, d_ws);
    vfe_fused<<<(K + 3) / 4, 256, 0, stream>>>(feat, nvx, d_ws, out, K);
}

// Round 12
// 72.203 us; speedup vs baseline: 1.1601x; 1.1601x over previous
//
#include <hip/hip_runtime.h>

constexpr float EPS = 1e-5f;

typedef __attribute__((ext_vector_type(8))) short bf16x8;
typedef __attribute__((ext_vector_type(4))) float f32x4;

// d_ws layout (bytes):
//   0      : w3p[8nt][4ks][64][8]  bf16, BN-folded. ks 0,1 = h2 rows (k<64); ks 2,3 = agg rows (k>=64)
//   32768  : w2p[2sel][4nt][64][8] bf16, BN-folded. sel0 = w2 rows 0-15 (h1), sel1 = rows 16-31 (agg); k-slots>=16 ZERO
//   40960  : w1p[64][8]            bf16, BN-folded, zeros for k>=8
//   41984  : bb1 f32[16] ; 42048: bb2 f32[64] ; 42304: bb3 f32[128]
#define W2P_OFF 32768
#define W1P_OFF 40960
#define B1_OFF  41984
#define B2_OFF  42048
#define B3_OFF  42304

__device__ __forceinline__ ushort f2bf(float x) {
    union { float f; unsigned u; } a; a.f = x;
    unsigned r = a.u + 0x7fffu + ((a.u >> 16) & 1u);   // RTNE (finite inputs only)
    return (ushort)(r >> 16);
}

__device__ __forceinline__ unsigned cvtpk(float lo, float hi) {
    unsigned r;
    asm("v_cvt_pk_bf16_f32 %0, %1, %2" : "=v"(r) : "v"(lo), "v"(hi));
    return r;
}

__global__ void vfe_prep(
    const float* __restrict__ w1, const float* __restrict__ b1,
    const float* __restrict__ g1, const float* __restrict__ be1,
    const float* __restrict__ m1, const float* __restrict__ v1,
    const float* __restrict__ w2, const float* __restrict__ b2,
    const float* __restrict__ g2, const float* __restrict__ be2,
    const float* __restrict__ m2, const float* __restrict__ v2,
    const float* __restrict__ w3, const float* __restrict__ b3,
    const float* __restrict__ g3, const float* __restrict__ be3,
    const float* __restrict__ m3, const float* __restrict__ v3,
    void* __restrict__ ws)
{
    ushort* w3p = (ushort*)ws;
    ushort* w2p = (ushort*)((char*)ws + W2P_OFF);
    ushort* w1p = (ushort*)((char*)ws + W1P_OFF);
    float*  bb1 = (float*)((char*)ws + B1_OFF);
    float*  bb2 = (float*)((char*)ws + B2_OFF);
    float*  bb3 = (float*)((char*)ws + B3_OFF);

    const int i = blockIdx.x * 256 + threadIdx.x;
    if (i < 16384) {                       // w3p: ((nt*4+ks)*64 + l)*8 + e
        const int e = i & 7, l = (i >> 3) & 63, rest = i >> 9;
        const int ks = rest & 3, nt = rest >> 2, g = l >> 4;
        const int k = ks * 32 + g * 8 + e;
        const int n = nt * 16 + (l & 15);
        const float s = g3[n] * rsqrtf(v3[n] + EPS);
        w3p[i] = f2bf(w3[k * 128 + n] * s);
    } else if (i < 20480) {                // w2p: ((sel*4+nt)*64 + l)*8 + e ; zeros k>=16
        const int j = i - 16384;
        const int e = j & 7, l = (j >> 3) & 63, rest = j >> 9;
        const int nt = rest & 3, sel = rest >> 2;
        const int klog = (l >> 4) * 8 + e;             // 0..31, real only <16
        const int n = nt * 16 + (l & 15);
        const float s = g2[n] * rsqrtf(v2[n] + EPS);
        w2p[j] = (klog < 16) ? f2bf(w2[(sel * 16 + klog) * 64 + n] * s) : (ushort)0;
    } else if (i < 20992) {                // w1p: l*8 + e, zeros for k>=8
        const int j = i - 20480;
        const int e = j & 7, l = j >> 3;
        const int klog = (l >> 4) * 8 + e;
        const int u = l & 15;
        const float s = g1[u] * rsqrtf(v1[u] + EPS);
        w1p[j] = (klog < 8) ? f2bf(w1[klog * 16 + u] * s) : (ushort)0;
    } else if (i < 21200) {
        const int j = i - 20992;
        if (j < 16) {
            const int u = j;
            bb1[u] = (b1[u] - m1[u]) * (g1[u] * rsqrtf(v1[u] + EPS)) + be1[u];
        } else if (j < 80) {
            const int u = j - 16;
            bb2[u] = (b2[u] - m2[u]) * (g2[u] * rsqrtf(v2[u] + EPS)) + be2[u];
        } else {
            const int u = j - 80;
            bb3[u] = (b3[u] - m3[u]) * (g3[u] * rsqrtf(v3[u] + EPS)) + be3[u];
        }
    }
}

#define NV(v)   ((v)==0?nv0:(v)==1?nv1:(v)==2?nv2:nv3)
#define LIM(v)  ((v)==0?lim0:(v)==1?lim1:(v)==2?lim2:lim3)
#define FULL(v) ((v)==0?full0:(v)==1?full1:(v)==2?full2:full3)

// 4 voxels per block, 256 threads / 4 waves. Tiles 3v..3v+2 = voxel v.
// R10 structure; R12 = cvtpk-packed staging + hoisted C-init splats + sX0 union.
__global__ __launch_bounds__(256, 4) void vfe_fused(
    const float* __restrict__ feat,
    const int* __restrict__ nvox,
    const void* __restrict__ ws,
    float* __restrict__ out,
    int K)
{
    __shared__ __align__(16) ushort sBfrag[12 * 2 * 64 * 8];// h2, fragment order (R8 layout)
    __shared__ __align__(16) ushort sAfrag[12 * 16 * 24];   // h1: [tile][row16][chan pad24]
    __shared__ __align__(16) ushort sAgg1bf[4][16];
    __shared__ __align__(16) ushort sAgg2bf[4][64];

    // sX0bf unioned into head of sBfrag: dead after L1; first sBfrag write (L2
    // epilogue) is after the post-L1 barrier -> safe. 192 rows x 16B = 3 KB.
    ushort (*sX0bf)[8] = (ushort(*)[8])&sBfrag[0];

    const ushort* w3p = (const ushort*)ws;
    const ushort* w2p = (const ushort*)((const char*)ws + W2P_OFF);
    const ushort* w1p = (const ushort*)((const char*)ws + W1P_OFF);
    const float*  bb1 = (const float*)((const char*)ws + B1_OFF);
    const float*  bb2 = (const float*)((const char*)ws + B2_OFF);
    const float*  bb3 = (const float*)((const char*)ws + B3_OFF);

    const int tid  = threadIdx.x;
    const int lane = tid & 63;
    const int w    = tid >> 6;
    const int g    = lane >> 4;
    const int m15  = lane & 15;
    const int kA   = blockIdx.x * 4;

    int kk0 = kA, kk1 = min(kA+1, K-1), kk2 = min(kA+2, K-1), kk3 = min(kA+3, K-1);
    int nv0 = __builtin_amdgcn_readfirstlane(nvox[kk0]);
    int nv1 = __builtin_amdgcn_readfirstlane(nvox[kk1]);
    int nv2 = __builtin_amdgcn_readfirstlane(nvox[kk2]);
    int nv3 = __builtin_amdgcn_readfirstlane(nvox[kk3]);
    const int lim0=(nv0+15)>>4, lim1=(nv1+15)>>4, lim2=(nv2+15)>>4, lim3=(nv3+15)>>4;
    const int full0=nv0>>4, full1=nv1>>4, full2=nv2>>4, full3=nv3>>4;

    union U8 { bf16x8 v; unsigned u[4]; };

    // ---- B-fragment preloads (L2-hot) ----
    const bf16x8 b1f   = *(const bf16x8*)(w1p + (size_t)lane * 8);
    const bf16x8 w2lof = *(const bf16x8*)(w2p + (size_t)((0 * 4 + w) * 64 + lane) * 8);
    const bf16x8 w2hif = *(const bf16x8*)(w2p + (size_t)((1 * 4 + w) * 64 + lane) * 8);
    bf16x8 b3f[2][4];
    #pragma unroll
    for (int nt = 0; nt < 2; ++nt)
        #pragma unroll
        for (int ks = 0; ks < 4; ++ks)
            b3f[nt][ks] = *(const bf16x8*)(w3p + (size_t)(((w * 2 + nt) * 4 + ks) * 64 + lane) * 8);

    // ---- stage 0: wave w -> voxel w ----
    {
        const int kkw = (w==0)?kk0:(w==1)?kk1:(w==2)?kk2:kk3;
        const int nvw = (w==0)?nv0:(w==1)?nv1:(w==2)?nv2:nv3;
        float4 f = make_float4(0.f, 0.f, 0.f, 0.f);
        if (lane < 48)
            f = *reinterpret_cast<const float4*>(feat + ((size_t)kkw * 48 + lane) * 4);
        float sx = f.x, sy = f.y, sz = f.z;
        #pragma unroll
        for (int d = 1; d < 64; d <<= 1) {
            sx += __shfl_xor(sx, d);
            sy += __shfl_xor(sy, d);
            sz += __shfl_xor(sz, d);
        }
        const float inv = 1.f / (float)nvw;
        if (lane < 48) {
            const float msk = (lane < nvw) ? 1.f : 0.f;
            const float dd = sqrtf(f.x * f.x + f.y * f.y + f.z * f.z);
            U8 a;
            a.u[0] = cvtpk(f.x * msk, f.y * msk);
            a.u[1] = cvtpk(f.z * msk, f.w * msk);
            a.u[2] = cvtpk((f.x - sx * inv) * msk, (f.y - sy * inv) * msk);
            a.u[3] = cvtpk((f.z - sz * inv) * msk, dd * msk);
            *reinterpret_cast<bf16x8*>(&sX0bf[w * 48 + lane][0]) = a.v;
        }
    }
    __syncthreads();

    // ---- layer 1 MFMA: wave w owns voxel w's 3 tiles; agg1 reduced in-wave ----
    {
        const float bb1u = bb1[m15];
        const int limw = (w==0)?lim0:(w==1)?lim1:(w==2)?lim2:lim3;
        const f32x4 ci = {bb1u, bb1u, bb1u, bb1u};
        float pmax = fmaxf(bb1u, 0.f);   // analytic masked-row term (nv<48 always)
        #pragma unroll
        for (int s = 0; s < 3; ++s) {
            if (s < limw) {
                const bf16x8 af = *(const bf16x8*)&sX0bf[w * 48 + s * 16 + m15][0];
                f32x4 acc = __builtin_amdgcn_mfma_f32_16x16x32_bf16(af, b1f, ci, 0, 0, 0);
                float h0 = fmaxf(acc[0], 0.f), h1 = fmaxf(acc[1], 0.f);
                float h2 = fmaxf(acc[2], 0.f), h3 = fmaxf(acc[3], 0.f);
                pmax = fmaxf(pmax, fmaxf(fmaxf(h0, h1), fmaxf(h2, h3)));
                const unsigned p01 = cvtpk(h0, h1), p23 = cvtpk(h2, h3);
                ushort* base = &sAfrag[((w * 3 + s) * 16 + g * 4) * 24 + m15];
                base[0]      = (ushort)p01;
                base[24]     = (ushort)(p01 >> 16);
                base[48]     = (ushort)p23;
                base[72]     = (ushort)(p23 >> 16);
            }
        }
        pmax = fmaxf(pmax, __shfl_xor(pmax, 16));
        pmax = fmaxf(pmax, __shfl_xor(pmax, 32));
        if (g == 0) sAgg1bf[w][m15] = f2bf(pmax);
    }
    __syncthreads();

    // ---- z2-fold MFMA: A rows cycle voxels (m15&3) -> C reg r = init for voxel r ----
    const int col2 = w * 16 + m15;
    const float bb2c = bb2[col2];
    f32x4 z2acc;
    {
        const bf16x8 az2 = *(const bf16x8*)&sAgg1bf[m15 & 3][(g & 1) * 8];
        f32x4 ci = {bb2c, bb2c, bb2c, bb2c};
        z2acc = __builtin_amdgcn_mfma_f32_16x16x32_bf16(az2, w2hif, ci, 0, 0, 0);
    }

    // ---- layer 2 MFMA in two 6-tile halves (C-init = bb2+z2, hoisted splats) ----
    {
        const int ks = col2 >> 5, gp = (col2 >> 3) & 3, e = col2 & 7;
        #pragma unroll
        for (int vg = 0; vg < 2; ++vg) {
            const f32x4 cP = {z2acc[vg*2],   z2acc[vg*2],   z2acc[vg*2],   z2acc[vg*2]};
            const f32x4 cQ = {z2acc[vg*2+1], z2acc[vg*2+1], z2acc[vg*2+1], z2acc[vg*2+1]};
            f32x4 acc2[6];
            #pragma unroll
            for (int j = 0; j < 6; ++j) {
                const int tt = vg * 6 + j;
                const int vox = vg * 2 + j / 3;
                const int mtl = j % 3;
                if (mtl < LIM(vox)) {
                    const bf16x8 af = *(const bf16x8*)&sAfrag[(tt * 16 + m15) * 24 + (g & 1) * 8];
                    acc2[j] = __builtin_amdgcn_mfma_f32_16x16x32_bf16(af, w2lof, (j < 3) ? cP : cQ, 0, 0, 0);
                }
            }
            float mxP = fmaxf(bb2c, 0.f);   // voxel vg*2   (analytic masked-row term)
            float mxQ = fmaxf(bb2c, 0.f);   // voxel vg*2+1
            #pragma unroll
            for (int j = 0; j < 6; ++j) {
                const int tt = vg * 6 + j;
                const int vox = vg * 2 + j / 3;
                const int mtl = j % 3;
                if (mtl < LIM(vox)) {
                    float h[4];
                    #pragma unroll
                    for (int r = 0; r < 4; ++r) h[r] = fmaxf(acc2[j][r], 0.f);
                    const unsigned p01 = cvtpk(h[0], h[1]), p23 = cvtpk(h[2], h[3]);
                    ushort* base = &sBfrag[((tt * 2 + ks) * 64 + gp * 16 + g * 4) * 8 + e];
                    base[0]  = (ushort)p01;
                    base[8]  = (ushort)(p01 >> 16);
                    base[16] = (ushort)p23;
                    base[24] = (ushort)(p23 >> 16);
                    if (mtl < FULL(vox)) {
                        const float t01 = fmaxf(h[0], h[1]), t23 = fmaxf(h[2], h[3]);
                        if (j < 3) mxP = fmaxf(mxP, fmaxf(t01, t23));
                        else       mxQ = fmaxf(mxQ, fmaxf(t01, t23));
                    } else {
                        #pragma unroll
                        for (int r = 0; r < 4; ++r) {
                            if (mtl * 16 + g * 4 + r < NV(vox)) {
                                if (j < 3) mxP = fmaxf(mxP, h[r]);
                                else       mxQ = fmaxf(mxQ, h[r]);
                            }
                        }
                    }
                }
            }
            mxP = fmaxf(mxP, __shfl_xor(mxP, 16));
            mxP = fmaxf(mxP, __shfl_xor(mxP, 32));
            mxQ = fmaxf(mxQ, __shfl_xor(mxQ, 16));
            mxQ = fmaxf(mxQ, __shfl_xor(mxQ, 32));
            if (g == 0) {
                sAgg2bf[vg * 2 + 0][col2] = f2bf(mxP);
                sAgg2bf[vg * 2 + 1][col2] = f2bf(mxQ);
            }
        }
    }
    __syncthreads();

    // ---- z3-fold (C-init = bb3; A rows cycle voxels) -> i3[nt][v] ----
    f32x4 i3[2];
    #pragma unroll
    for (int nt = 0; nt < 2; ++nt) {
        const float bb3c = bb3[(w * 2 + nt) * 16 + m15];
        f32x4 z = {bb3c, bb3c, bb3c, bb3c};
        #pragma unroll
        for (int ks2 = 0; ks2 < 2; ++ks2) {
            const bf16x8 af = *(const bf16x8*)&sAgg2bf[m15 & 3][ks2 * 32 + g * 8];
            z = __builtin_amdgcn_mfma_f32_16x16x32_bf16(af, b3f[nt][2 + ks2], z, 0, 0, 0);
        }
        i3[nt] = z;
    }

    // ---- layer 3 MFMA: 2 passes x two 6-tile halves (C-init = bb3+z3, hoisted splats) ----
    #pragma unroll
    for (int pass = 0; pass < 2; ++pass) {
        const int col = (w * 2 + pass) * 16 + m15;
        #pragma unroll
        for (int vg = 0; vg < 2; ++vg) {
            const f32x4 cP = {i3[pass][vg*2],   i3[pass][vg*2],   i3[pass][vg*2],   i3[pass][vg*2]};
            const f32x4 cQ = {i3[pass][vg*2+1], i3[pass][vg*2+1], i3[pass][vg*2+1], i3[pass][vg*2+1]};
            f32x4 acc3[6];
            #pragma unroll
            for (int j = 0; j < 6; ++j) {
                const int tt = vg * 6 + j;
                const int vox = vg * 2 + j / 3;
                const int mtl = j % 3;
                if (mtl < LIM(vox)) {
                    const bf16x8 af0 = *(const bf16x8*)&sBfrag[((tt * 2 + 0) * 64 + lane) * 8];
                    const bf16x8 af1 = *(const bf16x8*)&sBfrag[((tt * 2 + 1) * 64 + lane) * 8];
                    acc3[j] = __builtin_amdgcn_mfma_f32_16x16x32_bf16(af0, b3f[pass][0], (j < 3) ? cP : cQ, 0, 0, 0);
                    acc3[j] = __builtin_amdgcn_mfma_f32_16x16x32_bf16(af1, b3f[pass][1], acc3[j], 0, 0, 0);
                }
            }
            float mxP = 0.f, mxQ = 0.f;   // relu folded into fmax (mx >= 0)
            #pragma unroll
            for (int j = 0; j < 6; ++j) {
                const int vox = vg * 2 + j / 3;
                const int mtl = j % 3;
                if (mtl < FULL(vox)) {
                    const float t01 = fmaxf(acc3[j][0], acc3[j][1]);
                    const float t23 = fmaxf(acc3[j][2], acc3[j][3]);
                    if (j < 3) mxP = fmaxf(mxP, fmaxf(t01, t23));
                    else       mxQ = fmaxf(mxQ, fmaxf(t01, t23));
                } else if (mtl < LIM(vox)) {
                    #pragma unroll
                    for (int r = 0; r < 4; ++r) {
                        if (mtl * 16 + g * 4 + r < NV(vox)) {
                            if (j < 3) mxP = fmaxf(mxP, acc3[j][r]);
                            else       mxQ = fmaxf(mxQ, acc3[j][r]);
                        }
                    }
                }
            }
            mxP = fmaxf(mxP, __shfl_xor(mxP, 16));
            mxP = fmaxf(mxP, __shfl_xor(mxP, 32));
            mxQ = fmaxf(mxQ, __shfl_xor(mxQ, 16));
            mxQ = fmaxf(mxQ, __shfl_xor(mxQ, 32));
            if (g == (vg * 2 + 0) && (kA + vg * 2 + 0) < K) out[(size_t)(kA + vg * 2 + 0) * 128 + col] = mxP;
            if (g == (vg * 2 + 1) && (kA + vg * 2 + 1) < K) out[(size_t)(kA + vg * 2 + 1) * 128 + col] = mxQ;
        }
    }
}

extern "C" void kernel_launch(void* const* d_in, const int* in_sizes, int n_in,
                              void* d_out, int out_size, void* d_ws, size_t ws_size,
                              hipStream_t stream) {
    const float* feat = (const float*)d_in[0];
    const int*   nvx  = (const int*)d_in[1];
    const float* w1 = (const float*)d_in[3];
    const float* b1 = (const float*)d_in[4];
    const float* g1 = (const float*)d_in[5];
    const float* be1= (const float*)d_in[6];
    const float* m1 = (const float*)d_in[7];
    const float* v1 = (const float*)d_in[8];
    const float* w2 = (const float*)d_in[9];
    const float* b2 = (const float*)d_in[10];
    const float* g2 = (const float*)d_in[11];
    const float* be2= (const float*)d_in[12];
    const float* m2 = (const float*)d_in[13];
    const float* v2 = (const float*)d_in[14];
    const float* w3 = (const float*)d_in[15];
    const float* b3 = (const float*)d_in[16];
    const float* g3 = (const float*)d_in[17];
    const float* be3= (const float*)d_in[18];
    const float* m3 = (const float*)d_in[19];
    const float* v3 = (const float*)d_in[20];
    float* out = (float*)d_out;

    const int K = in_sizes[1];

    vfe_prep<<<84, 256, 0, stream>>>(w1,b1,g1,be1,m1,v1, w2,b2,g2,be2,m2,v2,
                                     w3,b3,g3,be3,m3,v3, d_ws);
    vfe_fused<<<(K + 3) / 4, 256, 0, stream>>>(feat, nvx, d_ws, out, K);
}

// Round 13
// 72.150 us; speedup vs baseline: 1.1610x; 1.0007x over previous
//
#include <hip/hip_runtime.h>

constexpr float EPS = 1e-5f;

typedef __attribute__((ext_vector_type(8))) short bf16x8;
typedef __attribute__((ext_vector_type(4))) float f32x4;

// d_ws layout (bytes):
//   0      : w3p[8nt][4ks][64][8]  bf16, BN-folded. ks 0,1 = h2 rows (k<64); ks 2,3 = agg rows (k>=64)
//   32768  : w2p[2sel][4nt][64][8] bf16, BN-folded. sel0 = w2 rows 0-15 (h1), sel1 = rows 16-31 (agg); k-slots>=16 ZERO
//   40960  : w1p[64][8]            bf16, BN-folded, zeros for k>=8
//   41984  : bb1 f32[16] ; 42048: bb2 f32[64] ; 42304: bb3 f32[128]
#define W2P_OFF 32768
#define W1P_OFF 40960
#define B1_OFF  41984
#define B2_OFF  42048
#define B3_OFF  42304

#define APAD 20   // sAfrag row stride in ushorts (40 B -> 2-way max bank aliasing)

__device__ __forceinline__ ushort f2bf(float x) {
    union { float f; unsigned u; } a; a.f = x;
    unsigned r = a.u + 0x7fffu + ((a.u >> 16) & 1u);   // RTNE (finite inputs only)
    return (ushort)(r >> 16);
}

__device__ __forceinline__ unsigned cvtpk(float lo, float hi) {
    unsigned r;
    asm("v_cvt_pk_bf16_f32 %0, %1, %2" : "=v"(r) : "v"(lo), "v"(hi));
    return r;
}

__global__ void vfe_prep(
    const float* __restrict__ w1, const float* __restrict__ b1,
    const float* __restrict__ g1, const float* __restrict__ be1,
    const float* __restrict__ m1, const float* __restrict__ v1,
    const float* __restrict__ w2, const float* __restrict__ b2,
    const float* __restrict__ g2, const float* __restrict__ be2,
    const float* __restrict__ m2, const float* __restrict__ v2,
    const float* __restrict__ w3, const float* __restrict__ b3,
    const float* __restrict__ g3, const float* __restrict__ be3,
    const float* __restrict__ m3, const float* __restrict__ v3,
    void* __restrict__ ws)
{
    ushort* w3p = (ushort*)ws;
    ushort* w2p = (ushort*)((char*)ws + W2P_OFF);
    ushort* w1p = (ushort*)((char*)ws + W1P_OFF);
    float*  bb1 = (float*)((char*)ws + B1_OFF);
    float*  bb2 = (float*)((char*)ws + B2_OFF);
    float*  bb3 = (float*)((char*)ws + B3_OFF);

    const int i = blockIdx.x * 256 + threadIdx.x;
    if (i < 16384) {                       // w3p: ((nt*4+ks)*64 + l)*8 + e
        const int e = i & 7, l = (i >> 3) & 63, rest = i >> 9;
        const int ks = rest & 3, nt = rest >> 2, g = l >> 4;
        const int k = ks * 32 + g * 8 + e;
        const int n = nt * 16 + (l & 15);
        const float s = g3[n] * rsqrtf(v3[n] + EPS);
        w3p[i] = f2bf(w3[k * 128 + n] * s);
    } else if (i < 20480) {                // w2p: ((sel*4+nt)*64 + l)*8 + e ; zeros k>=16
        const int j = i - 16384;
        const int e = j & 7, l = (j >> 3) & 63, rest = j >> 9;
        const int nt = rest & 3, sel = rest >> 2;
        const int klog = (l >> 4) * 8 + e;             // 0..31, real only <16
        const int n = nt * 16 + (l & 15);
        const float s = g2[n] * rsqrtf(v2[n] + EPS);
        w2p[j] = (klog < 16) ? f2bf(w2[(sel * 16 + klog) * 64 + n] * s) : (ushort)0;
    } else if (i < 20992) {                // w1p: l*8 + e, zeros for k>=8
        const int j = i - 20480;
        const int e = j & 7, l = j >> 3;
        const int klog = (l >> 4) * 8 + e;
        const int u = l & 15;
        const float s = g1[u] * rsqrtf(v1[u] + EPS);
        w1p[j] = (klog < 8) ? f2bf(w1[klog * 16 + u] * s) : (ushort)0;
    } else if (i < 21200) {
        const int j = i - 20992;
        if (j < 16) {
            const int u = j;
            bb1[u] = (b1[u] - m1[u]) * (g1[u] * rsqrtf(v1[u] + EPS)) + be1[u];
        } else if (j < 80) {
            const int u = j - 16;
            bb2[u] = (b2[u] - m2[u]) * (g2[u] * rsqrtf(v2[u] + EPS)) + be2[u];
        } else {
            const int u = j - 80;
            bb3[u] = (b3[u] - m3[u]) * (g3[u] * rsqrtf(v3[u] + EPS)) + be3[u];
        }
    }
}

#define NV(v)   ((v)==0?nv0:(v)==1?nv1:(v)==2?nv2:nv3)
#define LIM(v)  ((v)==0?lim0:(v)==1?lim1:(v)==2?lim2:lim3)
#define FULL(v) ((v)==0?full0:(v)==1?full1:(v)==2?full2:full3)

// 4 voxels per block, 256 threads / 4 waves. Tiles 3v..3v+2 = voxel v.
// R12 structure; R13 = 2 barriers (stage0->L1 is same-wave), APAD=20, setprio on L3.
__global__ __launch_bounds__(256, 4) void vfe_fused(
    const float* __restrict__ feat,
    const int* __restrict__ nvox,
    const void* __restrict__ ws,
    float* __restrict__ out,
    int K)
{
    __shared__ __align__(16) ushort sBfrag[12 * 2 * 64 * 8]; // h2, fragment order (R8 layout)
    __shared__ __align__(16) ushort sAfrag[12 * 16 * APAD];  // h1: [tile][row16][chan APAD]
    __shared__ __align__(16) ushort sAgg1bf[4][16];
    __shared__ __align__(16) ushort sAgg2bf[4][64];

    // sX0bf unioned into head of sBfrag: dead after L1; first sBfrag write (L2
    // epilogue) is after the post-L1 barrier -> safe. 192 rows x 16B = 3 KB.
    ushort (*sX0bf)[8] = (ushort(*)[8])&sBfrag[0];

    const ushort* w3p = (const ushort*)ws;
    const ushort* w2p = (const ushort*)((const char*)ws + W2P_OFF);
    const ushort* w1p = (const ushort*)((const char*)ws + W1P_OFF);
    const float*  bb1 = (const float*)((const char*)ws + B1_OFF);
    const float*  bb2 = (const float*)((const char*)ws + B2_OFF);
    const float*  bb3 = (const float*)((const char*)ws + B3_OFF);

    const int tid  = threadIdx.x;
    const int lane = tid & 63;
    const int w    = tid >> 6;
    const int g    = lane >> 4;
    const int m15  = lane & 15;
    const int kA   = blockIdx.x * 4;

    int kk0 = kA, kk1 = min(kA+1, K-1), kk2 = min(kA+2, K-1), kk3 = min(kA+3, K-1);
    int nv0 = __builtin_amdgcn_readfirstlane(nvox[kk0]);
    int nv1 = __builtin_amdgcn_readfirstlane(nvox[kk1]);
    int nv2 = __builtin_amdgcn_readfirstlane(nvox[kk2]);
    int nv3 = __builtin_amdgcn_readfirstlane(nvox[kk3]);
    const int lim0=(nv0+15)>>4, lim1=(nv1+15)>>4, lim2=(nv2+15)>>4, lim3=(nv3+15)>>4;
    const int full0=nv0>>4, full1=nv1>>4, full2=nv2>>4, full3=nv3>>4;

    union U8 { bf16x8 v; unsigned u[4]; };

    // ---- B-fragment preloads (L2-hot) ----
    const bf16x8 b1f   = *(const bf16x8*)(w1p + (size_t)lane * 8);
    const bf16x8 w2lof = *(const bf16x8*)(w2p + (size_t)((0 * 4 + w) * 64 + lane) * 8);
    const bf16x8 w2hif = *(const bf16x8*)(w2p + (size_t)((1 * 4 + w) * 64 + lane) * 8);
    bf16x8 b3f[2][4];
    #pragma unroll
    for (int nt = 0; nt < 2; ++nt)
        #pragma unroll
        for (int ks = 0; ks < 4; ++ks)
            b3f[nt][ks] = *(const bf16x8*)(w3p + (size_t)(((w * 2 + nt) * 4 + ks) * 64 + lane) * 8);

    // ---- stage 0: wave w -> voxel w (no barrier after: L1 reads own-wave region only) ----
    {
        const int kkw = (w==0)?kk0:(w==1)?kk1:(w==2)?kk2:kk3;
        const int nvw = (w==0)?nv0:(w==1)?nv1:(w==2)?nv2:nv3;
        float4 f = make_float4(0.f, 0.f, 0.f, 0.f);
        if (lane < 48)
            f = *reinterpret_cast<const float4*>(feat + ((size_t)kkw * 48 + lane) * 4);
        float sx = f.x, sy = f.y, sz = f.z;
        #pragma unroll
        for (int d = 1; d < 64; d <<= 1) {
            sx += __shfl_xor(sx, d);
            sy += __shfl_xor(sy, d);
            sz += __shfl_xor(sz, d);
        }
        const float inv = 1.f / (float)nvw;
        if (lane < 48) {
            const float msk = (lane < nvw) ? 1.f : 0.f;
            const float dd = sqrtf(f.x * f.x + f.y * f.y + f.z * f.z);
            U8 a;
            a.u[0] = cvtpk(f.x * msk, f.y * msk);
            a.u[1] = cvtpk(f.z * msk, f.w * msk);
            a.u[2] = cvtpk((f.x - sx * inv) * msk, (f.y - sy * inv) * msk);
            a.u[3] = cvtpk((f.z - sz * inv) * msk, dd * msk);
            *reinterpret_cast<bf16x8*>(&sX0bf[w * 48 + lane][0]) = a.v;
        }
    }
    // NOTE: no __syncthreads here — stage0->L1 is a same-wave LDS dependency
    // (wave w writes sX0bf[w*48+..], wave w reads sX0bf[w*48+..]); the compiler
    // orders it with lgkmcnt. Cross-wave consumers are all after the next barrier.

    // ---- layer 1 MFMA: wave w owns voxel w's 3 tiles; agg1 reduced in-wave ----
    {
        const float bb1u = bb1[m15];
        const int limw = (w==0)?lim0:(w==1)?lim1:(w==2)?lim2:lim3;
        const f32x4 ci = {bb1u, bb1u, bb1u, bb1u};
        float pmax = fmaxf(bb1u, 0.f);   // analytic masked-row term (nv<48 always)
        #pragma unroll
        for (int s = 0; s < 3; ++s) {
            if (s < limw) {
                const bf16x8 af = *(const bf16x8*)&sX0bf[w * 48 + s * 16 + m15][0];
                f32x4 acc = __builtin_amdgcn_mfma_f32_16x16x32_bf16(af, b1f, ci, 0, 0, 0);
                float h0 = fmaxf(acc[0], 0.f), h1 = fmaxf(acc[1], 0.f);
                float h2 = fmaxf(acc[2], 0.f), h3 = fmaxf(acc[3], 0.f);
                pmax = fmaxf(pmax, fmaxf(fmaxf(h0, h1), fmaxf(h2, h3)));
                const unsigned p01 = cvtpk(h0, h1), p23 = cvtpk(h2, h3);
                ushort* base = &sAfrag[((w * 3 + s) * 16 + g * 4) * APAD + m15];
                base[0 * APAD] = (ushort)p01;
                base[1 * APAD] = (ushort)(p01 >> 16);
                base[2 * APAD] = (ushort)p23;
                base[3 * APAD] = (ushort)(p23 >> 16);
            }
        }
        pmax = fmaxf(pmax, __shfl_xor(pmax, 16));
        pmax = fmaxf(pmax, __shfl_xor(pmax, 32));
        if (g == 0) sAgg1bf[w][m15] = f2bf(pmax);
    }
    __syncthreads();

    // ---- z2-fold MFMA: A rows cycle voxels (m15&3) -> C reg r = init for voxel r ----
    const int col2 = w * 16 + m15;
    const float bb2c = bb2[col2];
    f32x4 z2acc;
    {
        const bf16x8 az2 = *(const bf16x8*)&sAgg1bf[m15 & 3][(g & 1) * 8];
        f32x4 ci = {bb2c, bb2c, bb2c, bb2c};
        z2acc = __builtin_amdgcn_mfma_f32_16x16x32_bf16(az2, w2hif, ci, 0, 0, 0);
    }

    // ---- layer 2 MFMA in two 6-tile halves (C-init = bb2+z2, hoisted splats) ----
    {
        const int ks = col2 >> 5, gp = (col2 >> 3) & 3, e = col2 & 7;
        #pragma unroll
        for (int vg = 0; vg < 2; ++vg) {
            const f32x4 cP = {z2acc[vg*2],   z2acc[vg*2],   z2acc[vg*2],   z2acc[vg*2]};
            const f32x4 cQ = {z2acc[vg*2+1], z2acc[vg*2+1], z2acc[vg*2+1], z2acc[vg*2+1]};
            f32x4 acc2[6];
            #pragma unroll
            for (int j = 0; j < 6; ++j) {
                const int tt = vg * 6 + j;
                const int vox = vg * 2 + j / 3;
                const int mtl = j % 3;
                if (mtl < LIM(vox)) {
                    const bf16x8 af = *(const bf16x8*)&sAfrag[(tt * 16 + m15) * APAD + (g & 1) * 8];
                    acc2[j] = __builtin_amdgcn_mfma_f32_16x16x32_bf16(af, w2lof, (j < 3) ? cP : cQ, 0, 0, 0);
                }
            }
            float mxP = fmaxf(bb2c, 0.f);   // voxel vg*2   (analytic masked-row term)
            float mxQ = fmaxf(bb2c, 0.f);   // voxel vg*2+1
            #pragma unroll
            for (int j = 0; j < 6; ++j) {
                const int tt = vg * 6 + j;
                const int vox = vg * 2 + j / 3;
                const int mtl = j % 3;
                if (mtl < LIM(vox)) {
                    float h[4];
                    #pragma unroll
                    for (int r = 0; r < 4; ++r) h[r] = fmaxf(acc2[j][r], 0.f);
                    const unsigned p01 = cvtpk(h[0], h[1]), p23 = cvtpk(h[2], h[3]);
                    ushort* base = &sBfrag[((tt * 2 + ks) * 64 + gp * 16 + g * 4) * 8 + e];
                    base[0]  = (ushort)p01;
                    base[8]  = (ushort)(p01 >> 16);
                    base[16] = (ushort)p23;
                    base[24] = (ushort)(p23 >> 16);
                    if (mtl < FULL(vox)) {
                        const float t01 = fmaxf(h[0], h[1]), t23 = fmaxf(h[2], h[3]);
                        if (j < 3) mxP = fmaxf(mxP, fmaxf(t01, t23));
                        else       mxQ = fmaxf(mxQ, fmaxf(t01, t23));
                    } else {
                        #pragma unroll
                        for (int r = 0; r < 4; ++r) {
                            if (mtl * 16 + g * 4 + r < NV(vox)) {
                                if (j < 3) mxP = fmaxf(mxP, h[r]);
                                else       mxQ = fmaxf(mxQ, h[r]);
                            }
                        }
                    }
                }
            }
            mxP = fmaxf(mxP, __shfl_xor(mxP, 16));
            mxP = fmaxf(mxP, __shfl_xor(mxP, 32));
            mxQ = fmaxf(mxQ, __shfl_xor(mxQ, 16));
            mxQ = fmaxf(mxQ, __shfl_xor(mxQ, 32));
            if (g == 0) {
                sAgg2bf[vg * 2 + 0][col2] = f2bf(mxP);
                sAgg2bf[vg * 2 + 1][col2] = f2bf(mxQ);
            }
        }
    }
    __syncthreads();

    // ---- z3-fold (C-init = bb3; A rows cycle voxels) -> i3[nt][v] ----
    f32x4 i3[2];
    #pragma unroll
    for (int nt = 0; nt < 2; ++nt) {
        const float bb3c = bb3[(w * 2 + nt) * 16 + m15];
        f32x4 z = {bb3c, bb3c, bb3c, bb3c};
        #pragma unroll
        for (int ks2 = 0; ks2 < 2; ++ks2) {
            const bf16x8 af = *(const bf16x8*)&sAgg2bf[m15 & 3][ks2 * 32 + g * 8];
            z = __builtin_amdgcn_mfma_f32_16x16x32_bf16(af, b3f[nt][2 + ks2], z, 0, 0, 0);
        }
        i3[nt] = z;
    }

    // ---- layer 3 MFMA: 2 passes x two 6-tile halves (C-init = bb3+z3, hoisted splats) ----
    #pragma unroll
    for (int pass = 0; pass < 2; ++pass) {
        const int col = (w * 2 + pass) * 16 + m15;
        #pragma unroll
        for (int vg = 0; vg < 2; ++vg) {
            const f32x4 cP = {i3[pass][vg*2],   i3[pass][vg*2],   i3[pass][vg*2],   i3[pass][vg*2]};
            const f32x4 cQ = {i3[pass][vg*2+1], i3[pass][vg*2+1], i3[pass][vg*2+1], i3[pass][vg*2+1]};
            f32x4 acc3[6];
            __builtin_amdgcn_s_setprio(1);
            #pragma unroll
            for (int j = 0; j < 6; ++j) {
                const int tt = vg * 6 + j;
                const int vox = vg * 2 + j / 3;
                const int mtl = j % 3;
                if (mtl < LIM(vox)) {
                    const bf16x8 af0 = *(const bf16x8*)&sBfrag[((tt * 2 + 0) * 64 + lane) * 8];
                    const bf16x8 af1 = *(const bf16x8*)&sBfrag[((tt * 2 + 1) * 64 + lane) * 8];
                    acc3[j] = __builtin_amdgcn_mfma_f32_16x16x32_bf16(af0, b3f[pass][0], (j < 3) ? cP : cQ, 0, 0, 0);
                    acc3[j] = __builtin_amdgcn_mfma_f32_16x16x32_bf16(af1, b3f[pass][1], acc3[j], 0, 0, 0);
                }
            }
            __builtin_amdgcn_s_setprio(0);
            float mxP = 0.f, mxQ = 0.f;   // relu folded into fmax (mx >= 0)
            #pragma unroll
            for (int j = 0; j < 6; ++j) {
                const int vox = vg * 2 + j / 3;
                const int mtl = j % 3;
                if (mtl < FULL(vox)) {
                    const float t01 = fmaxf(acc3[j][0], acc3[j][1]);
                    const float t23 = fmaxf(acc3[j][2], acc3[j][3]);
                    if (j < 3) mxP = fmaxf(mxP, fmaxf(t01, t23));
                    else       mxQ = fmaxf(mxQ, fmaxf(t01, t23));
                } else if (mtl < LIM(vox)) {
                    #pragma unroll
                    for (int r = 0; r < 4; ++r) {
                        if (mtl * 16 + g * 4 + r < NV(vox)) {
                            if (j < 3) mxP = fmaxf(mxP, acc3[j][r]);
                            else       mxQ = fmaxf(mxQ, acc3[j][r]);
                        }
                    }
                }
            }
            mxP = fmaxf(mxP, __shfl_xor(mxP, 16));
            mxP = fmaxf(mxP, __shfl_xor(mxP, 32));
            mxQ = fmaxf(mxQ, __shfl_xor(mxQ, 16));
            mxQ = fmaxf(mxQ, __shfl_xor(mxQ, 32));
            if (g == (vg * 2 + 0) && (kA + vg * 2 + 0) < K) out[(size_t)(kA + vg * 2 + 0) * 128 + col] = mxP;
            if (g == (vg * 2 + 1) && (kA + vg * 2 + 1) < K) out[(size_t)(kA + vg * 2 + 1) * 128 + col] = mxQ;
        }
    }
}

extern "C" void kernel_launch(void* const* d_in, const int* in_sizes, int n_in,
                              void* d_out, int out_size, void* d_ws, size_t ws_size,
                              hipStream_t stream) {
    const float* feat = (const float*)d_in[0];
    const int*   nvx  = (const int*)d_in[1];
    const float* w1 = (const float*)d_in[3];
    const float* b1 = (const float*)d_in[4];
    const float* g1 = (const float*)d_in[5];
    const float* be1= (const float*)d_in[6];
    const float* m1 = (const float*)d_in[7];
    const float* v1 = (const float*)d_in[8];
    const float* w2 = (const float*)d_in[9];
    const float* b2 = (const float*)d_in[10];
    const float* g2 = (const float*)d_in[11];
    const float* be2= (const float*)d_in[12];
    const float* m2 = (const float*)d_in[13];
    const float* v2 = (const float*)d_in[14];
    const float* w3 = (const float*)d_in[15];
    const float* b3 = (const float*)d_in[16];
    const float* g3 = (const float*)d_in[17];
    const float* be3= (const float*)d_in[18];
    const float* m3 = (const float*)d_in[19];
    const float* v3 = (const float*)d_in[20];
    float* out = (float*)d_out;

    const int K = in_sizes[1];

    vfe_prep<<<84, 256, 0, stream>>>(w1,b1,g1,be1,m1,v1, w2,b2,g2,be2,m2,v2,
                                     w3,b3,g3,be3,m3,v3, d_ws);
    vfe_fused<<<(K + 3) / 4, 256, 0, stream>>>(feat, nvx, d_ws, out, K);
}